// Round 8
// baseline (70.314 us; speedup 1.0000x reference)
//
#include <hip/hip_runtime.h>
#include <math.h>

constexpr int In = 128, Rn = 36, Cn = 64, Ln = 32, Dn = 512;
constexpr int Mn = In * Rn;              // 4608
constexpr int Nn = Cn * Ln;              // 2048
// ws layout (float units)
constexpr size_t ABOFF = 0;                            // images bf16 (Mn*Dn u16)
constexpr size_t BBOFF = (size_t)Mn * Dn / 2;          // captions bf16
constexpr size_t GBOFF = BBOFF + (size_t)Nn * Dn / 2;  // Gb bf16 [In][48][64]
constexpr size_t CNOFF = GBOFF + (size_t)In * 48 * 64 / 2;
constexpr size_t WSFLOATS = CNOFF + (size_t)Cn * Ln;   // ~7.6 MB
constexpr float EPSf = 1e-8f, LLSE = 6.0f, LSM = 9.0f, SLOPE = 0.1f;

using short8 = __attribute__((ext_vector_type(8))) short;
using f32x4  = __attribute__((ext_vector_type(4))) float;

__device__ __forceinline__ float dot4(float4 a, float4 b) {
  return a.x * b.x + a.y * b.y + a.z * b.z + a.w * b.w;
}

__device__ __forceinline__ unsigned short f2bf(float x) {   // RNE
  union { float f; unsigned u; } v; v.f = x;
  unsigned r = v.u + 0x7fffu + ((v.u >> 16) & 1u);
  return (unsigned short)(r >> 16);
}

__device__ __forceinline__ short8 pack8(float4 u, float4 v) {
  short8 s;
  s[0] = (short)f2bf(u.x); s[1] = (short)f2bf(u.y); s[2] = (short)f2bf(u.z); s[3] = (short)f2bf(u.w);
  s[4] = (short)f2bf(v.x); s[5] = (short)f2bf(v.y); s[6] = (short)f2bf(v.z); s[7] = (short)f2bf(v.w);
  return s;
}

// ---------------------------------------------------------------------------
// Merged pre-pass. blocks 0..1663: fp32->bf16 cvt of images+captions.
// blocks 1664..1919: G[i] halves (bf16 [48][64]). blocks 1920..1983: cap norms.
// ---------------------------------------------------------------------------
extern "C" __global__ __launch_bounds__(256, 2)
void scan_pre(const float* __restrict__ images, const float* __restrict__ captions,
              float* __restrict__ ws)
{
  __shared__ float sm[Rn * 132];
  const int tid = threadIdx.x;
  if (blockIdx.x < 1664) {
    const int chunk = blockIdx.x * 256 + tid;
    const float* src;
    unsigned short* dst;
    size_t off;
    if (chunk < (Mn * Dn) / 8) {
      src = images; dst = (unsigned short*)(ws + ABOFF); off = (size_t)chunk * 8;
    } else {
      src = captions; dst = (unsigned short*)(ws + BBOFF);
      off = (size_t)(chunk - (Mn * Dn) / 8) * 8;
    }
    float4 u = *reinterpret_cast<const float4*>(src + off);
    float4 v = *reinterpret_cast<const float4*>(src + off + 4);
    *reinterpret_cast<short8*>(dst + off) = pack8(u, v);
    return;
  }
  unsigned short* GbAll = (unsigned short*)(ws + GBOFF);
  if (blockIdx.x < 1920) {
    const int bx = blockIdx.x - 1664;
    const int i = bx >> 1, half = bx & 1;
    const float* gi = images + (size_t)i * Rn * Dn;
    unsigned short* gb = GbAll + (size_t)i * 48 * 64;
    float acc[3] = {0.f, 0.f, 0.f};
    for (int ch = 0; ch < 4; ++ch) {
      __syncthreads();
      #pragma unroll
      for (int t = 0; t < 5; ++t) {
        int idx = tid + t * 256;
        if (idx < Rn * 32) {
          int r = idx >> 5, d4 = idx & 31;
          *reinterpret_cast<float4*>(&sm[r * 132 + d4 * 4]) =
            *reinterpret_cast<const float4*>(gi + r * Dn + ch * 128 + d4 * 4);
        }
      }
      __syncthreads();
      #pragma unroll
      for (int q = 0; q < 3; ++q) {
        int eo = tid + q * 256;
        if (eo < 648) {
          int e = half * 648 + eo;
          int r = e / Rn, rp = e - r * Rn;
          float s = 0.f;
          for (int s4 = 0; s4 < 32; ++s4)
            s += dot4(*reinterpret_cast<const float4*>(&sm[r * 132 + s4 * 4]),
                      *reinterpret_cast<const float4*>(&sm[rp * 132 + s4 * 4]));
          acc[q] += s;
        }
      }
    }
    #pragma unroll
    for (int q = 0; q < 3; ++q) {
      int eo = tid + q * 256;
      if (eo < 648) {
        int e = half * 648 + eo;
        int r = e / Rn, rp = e - r * Rn;
        gb[r * 64 + rp] = f2bf(acc[q]);
      }
    }
    for (int idx = tid; idx < 18 * 28; idx += 256) {
      int rr = half * 18 + idx / 28, cc = 36 + idx % 28;
      gb[rr * 64 + cc] = 0;
    }
    for (int idx = tid; idx < 6 * 64; idx += 256) {
      int rr = 36 + half * 6 + (idx >> 6);
      gb[rr * 64 + (idx & 63)] = 0;
    }
  } else {
    const int c = blockIdx.x - 1920;
    const float* gc = captions + (size_t)c * Ln * Dn;
    const int l = tid >> 3, p = tid & 7;
    float s = 0.f;
    #pragma unroll
    for (int t = 0; t < 16; ++t) {
      float4 v = *reinterpret_cast<const float4*>(gc + l * Dn + p * 64 + t * 4);
      s += dot4(v, v);
    }
    s += __shfl_xor(s, 1, 64); s += __shfl_xor(s, 2, 64); s += __shfl_xor(s, 4, 64);
    if (p == 0) ws[CNOFF + c * Ln + l] = s;
  }
}

// ---------------------------------------------------------------------------
// Fused: block = 1 image x 4 captions (wave = caption). A double-buffered in
// LDS (1 barrier/K-step); B-fragments direct from global, pipelined 1 step.
// Epilogue: leaky/mask/norm/softmax/num in regs, wn via second MFMA vs Gb.
// ---------------------------------------------------------------------------
extern "C" __global__ __launch_bounds__(256, 4)
void scan_fused(const float* __restrict__ ws, const int* __restrict__ cap_lens,
                float* __restrict__ out)
{
  __shared__ unsigned short Al[2][48 * 72];   // 13.8 KB
  __shared__ unsigned short ETb[4][32 * 72];  // 18.4 KB (per-wave private)
  const unsigned short* Ab = (const unsigned short*)(ws + ABOFF);
  const unsigned short* Bb = (const unsigned short*)(ws + BBOFF);
  const unsigned short* GbAll = (const unsigned short*)(ws + GBOFF);
  const float* cnArr = ws + CNOFF;

  const int tid = threadIdx.x;
  int bid = blockIdx.x;                      // 2048 blocks; 8 XCD chunks of 256
  bid = (bid & 7) * 256 + (bid >> 3);
  const int ig = bid >> 4;                   // image
  const int cg = bid & 15;                   // caption group (4 captions)
  const int lane = tid & 63, wv = tid >> 6;
  const int lr = lane & 15, lk = lane >> 4;
  const int cap = cg * 4 + wv;
  const int len = cap_lens[cap];

  // A staging coords (threads 0..191 cover 48 rows x 4 sixteen-col quarters)
  const int ar = tid >> 2, aq = tid & 3;
  const bool aLoad = (tid < 192) && (ar < 36);
  const bool aPad  = (tid < 192) && (ar >= 36);
  const unsigned short* gA = Ab + ((size_t)ig * 36 + (ar < 36 ? ar : 0)) * Dn + aq * 16;
  unsigned short* wA0 = &Al[0][ar * 72 + aq * 16];
  unsigned short* wA1 = &Al[1][ar * 72 + aq * 16];

  // B fragment base (per-lane, direct global)
  const unsigned short* gBf = Bb + ((size_t)(cg * 128) + wv * 32 + lr) * Dn + lk * 8;

  f32x4 acc[3][2];
  #pragma unroll
  for (int x = 0; x < 3; ++x)
    #pragma unroll
    for (int y = 0; y < 2; ++y) acc[x][y] = {0.f, 0.f, 0.f, 0.f};

  const short8 z8 = {0, 0, 0, 0, 0, 0, 0, 0};

  // prologue: A step0 -> buf0, pad rows zeroed in BOTH buffers; B regs step0
  if (aLoad) {
    *reinterpret_cast<short8*>(wA0)     = *reinterpret_cast<const short8*>(gA);
    *reinterpret_cast<short8*>(wA0 + 8) = *reinterpret_cast<const short8*>(gA + 8);
  } else if (aPad) {
    *reinterpret_cast<short8*>(wA0)     = z8;
    *reinterpret_cast<short8*>(wA0 + 8) = z8;
    *reinterpret_cast<short8*>(wA1)     = z8;
    *reinterpret_cast<short8*>(wA1 + 8) = z8;
  }
  short8 bc[2][2], bn[2][2];
  #pragma unroll
  for (int y = 0; y < 2; ++y)
    #pragma unroll
    for (int ks = 0; ks < 2; ++ks)
      bc[y][ks] = *reinterpret_cast<const short8*>(gBf + (size_t)y * 16 * Dn + ks * 32);

  for (int t = 0; t < 8; ++t) {
    const int k0 = t * 64;
    __syncthreads();                         // buf[t&1] ready; prefetches drained
    short8 a0n, a1n;
    if (t < 7) {
      if (aLoad) {
        a0n = *reinterpret_cast<const short8*>(gA + k0 + 64);
        a1n = *reinterpret_cast<const short8*>(gA + k0 + 72);
      }
      #pragma unroll
      for (int y = 0; y < 2; ++y)
        #pragma unroll
        for (int ks = 0; ks < 2; ++ks)
          bn[y][ks] = *reinterpret_cast<const short8*>(gBf + (size_t)y * 16 * Dn + k0 + 64 + ks * 32);
    }
    const unsigned short* Ar = Al[t & 1];
    #pragma unroll
    for (int ks = 0; ks < 2; ++ks) {
      short8 af[3];
      #pragma unroll
      for (int x = 0; x < 3; ++x)
        af[x] = *reinterpret_cast<const short8*>(&Ar[(x * 16 + lr) * 72 + ks * 32 + lk * 8]);
      #pragma unroll
      for (int x = 0; x < 3; ++x)
        #pragma unroll
        for (int y = 0; y < 2; ++y)
          acc[x][y] = __builtin_amdgcn_mfma_f32_16x16x32_bf16(af[x], bc[y][ks], acc[x][y], 0, 0, 0);
    }
    if (t < 7) {
      if (aLoad) {
        unsigned short* w = (t & 1) ? wA0 : wA1;
        *reinterpret_cast<short8*>(w)     = a0n;
        *reinterpret_cast<short8*>(w + 8) = a1n;
      }
      #pragma unroll
      for (int y = 0; y < 2; ++y)
        #pragma unroll
        for (int ks = 0; ks < 2; ++ks)
          bc[y][ks] = bn[y][ks];
    }
  }

  // ---- epilogue (per wave = per caption) ----
  float s[3][2][4];
  #pragma unroll
  for (int x = 0; x < 3; ++x)
    #pragma unroll
    for (int y = 0; y < 2; ++y) {
      const int l = y * 16 + lr;
      #pragma unroll
      for (int j = 0; j < 4; ++j) {
        float v = acc[x][y][j];
        v = v > 0.f ? v : SLOPE * v;
        if (l >= len) v = 0.f;
        s[x][y][j] = v;
      }
    }

  float zinv[3][4];
  #pragma unroll
  for (int x = 0; x < 3; ++x)
    #pragma unroll
    for (int j = 0; j < 4; ++j) {
      float t = s[x][0][j] * s[x][0][j] + s[x][1][j] * s[x][1][j];
      t += __shfl_xor(t, 1, 64); t += __shfl_xor(t, 2, 64);
      t += __shfl_xor(t, 4, 64); t += __shfl_xor(t, 8, 64);
      zinv[x][j] = LSM / (sqrtf(t) + EPSf);
    }

  const bool x2ok = (lk == 0);
  float mcol[2] = {-1e30f, -1e30f};
  #pragma unroll
  for (int x = 0; x < 3; ++x)
    #pragma unroll
    for (int y = 0; y < 2; ++y)
      #pragma unroll
      for (int j = 0; j < 4; ++j) {
        float zz = s[x][y][j] * zinv[x][j];
        s[x][y][j] = zz;
        if (x < 2 || x2ok) mcol[y] = fmaxf(mcol[y], zz);
      }
  #pragma unroll
  for (int y = 0; y < 2; ++y) {
    mcol[y] = fmaxf(mcol[y], __shfl_xor(mcol[y], 16, 64));
    mcol[y] = fmaxf(mcol[y], __shfl_xor(mcol[y], 32, 64));
  }

  float e[3][2][4];
  float esum[2] = {0.f, 0.f}, num[2] = {0.f, 0.f};
  #pragma unroll
  for (int x = 0; x < 3; ++x)
    #pragma unroll
    for (int y = 0; y < 2; ++y)
      #pragma unroll
      for (int j = 0; j < 4; ++j) {
        float ev = (x < 2 || x2ok) ? expf(s[x][y][j] - mcol[y]) : 0.f;
        e[x][y][j] = ev;
        esum[y] += ev;
        num[y] = fmaf(ev, acc[x][y][j], num[y]);
      }
  #pragma unroll
  for (int y = 0; y < 2; ++y) {
    esum[y] += __shfl_xor(esum[y], 16, 64); esum[y] += __shfl_xor(esum[y], 32, 64);
    num[y]  += __shfl_xor(num[y], 16, 64);  num[y]  += __shfl_xor(num[y], 32, 64);
  }

  // E^T (bf16) into this wave's private region: [l(32)][r pad 64], stride 72
  unsigned short* ET = ETb[wv];
  {
    const int zl = lane >> 1, zs = lane & 1;
    *reinterpret_cast<short8*>(&ET[zl * 72 + 48 + zs * 8]) = z8;
  }
  #pragma unroll
  for (int x = 0; x < 3; ++x)
    #pragma unroll
    for (int y = 0; y < 2; ++y)
      #pragma unroll
      for (int j = 0; j < 4; ++j)
        ET[(y * 16 + lr) * 72 + (x * 16 + lk * 4 + j)] = f2bf(e[x][y][j]);
  // wave-private LDS region: compiler-inserted lgkmcnt orders write->read

  const unsigned short* Gb = GbAll + (size_t)ig * 48 * 64;
  f32x4 vac[3][2];
  #pragma unroll
  for (int x = 0; x < 3; ++x)
    #pragma unroll
    for (int y = 0; y < 2; ++y) vac[x][y] = {0.f, 0.f, 0.f, 0.f};
  #pragma unroll
  for (int ks = 0; ks < 2; ++ks) {
    short8 efr[2];
    #pragma unroll
    for (int y = 0; y < 2; ++y)
      efr[y] = *reinterpret_cast<const short8*>(&ET[(y * 16 + lr) * 72 + ks * 32 + lk * 8]);
    #pragma unroll
    for (int x = 0; x < 3; ++x) {
      short8 gfr = *reinterpret_cast<const short8*>(Gb + (x * 16 + lr) * 64 + ks * 32 + lk * 8);
      #pragma unroll
      for (int y = 0; y < 2; ++y)
        vac[x][y] = __builtin_amdgcn_mfma_f32_16x16x32_bf16(gfr, efr[y], vac[x][y], 0, 0, 0);
    }
  }
  float wn[2] = {0.f, 0.f};
  #pragma unroll
  for (int x = 0; x < 3; ++x)
    #pragma unroll
    for (int y = 0; y < 2; ++y)
      #pragma unroll
      for (int j = 0; j < 4; ++j)
        wn[y] = fmaf(e[x][y][j], vac[x][y][j], wn[y]);
  #pragma unroll
  for (int y = 0; y < 2; ++y) {
    wn[y] += __shfl_xor(wn[y], 16, 64); wn[y] += __shfl_xor(wn[y], 32, 64);
  }

  const float cn0 = cnArr[cap * 32 + lr];
  const float cn1 = cnArr[cap * 32 + 16 + lr];
  float sc[2];
  #pragma unroll
  for (int y = 0; y < 2; ++y) {
    const int l = y * 16 + lr;
    const float cn = y ? cn1 : cn0;
    float inv = 1.f / esum[y];
    float nm = num[y] * inv;
    float w = fmaxf(wn[y], 0.f) * inv * inv;
    float den = fmaxf(sqrtf(cn), EPSf) * fmaxf(sqrtf(w), EPSf);
    sc[y] = (l < len) ? (nm / den) * LLSE : -INFINITY;
  }
  float mx = fmaxf(sc[0], sc[1]);
  mx = fmaxf(mx, __shfl_xor(mx, 1, 64)); mx = fmaxf(mx, __shfl_xor(mx, 2, 64));
  mx = fmaxf(mx, __shfl_xor(mx, 4, 64)); mx = fmaxf(mx, __shfl_xor(mx, 8, 64));
  float ex = expf(sc[0] - mx) + expf(sc[1] - mx);
  ex += __shfl_xor(ex, 1, 64); ex += __shfl_xor(ex, 2, 64);
  ex += __shfl_xor(ex, 4, 64); ex += __shfl_xor(ex, 8, 64);
  if (lane == 0) out[ig * Cn + cap] = (mx + logf(ex)) / LLSE;
}

extern "C" void kernel_launch(void* const* d_in, const int* in_sizes, int n_in,
                              void* d_out, int out_size, void* d_ws, size_t ws_size,
                              hipStream_t stream) {
  const float* images   = (const float*)d_in[0];
  const float* captions = (const float*)d_in[1];
  const int*   cap_lens = (const int*)d_in[2];
  float* out = (float*)d_out;
  float* ws  = (float*)d_ws;
  if (ws_size < WSFLOATS * sizeof(float)) return;

  hipLaunchKernelGGL(scan_pre, dim3(1984), dim3(256), 0, stream,
                     images, captions, ws);
  hipLaunchKernelGGL(scan_fused, dim3(In * 16), dim3(256), 0, stream,
                     ws, cap_lens, out);
}

// Round 9
// 45.197 us; speedup vs baseline: 1.5557x; 1.5557x over previous
//
#include <hip/hip_runtime.h>
#include <math.h>

constexpr int In = 128, Rn = 36, Cn = 64, Ln = 32, Dn = 512;
constexpr int Mn = In * Rn;              // 4608
constexpr int Nn = Cn * Ln;              // 2048
// ws layout (float units)
constexpr size_t ABOFF = 0;                            // images bf16 (Mn*Dn u16)
constexpr size_t BBOFF = (size_t)Mn * Dn / 2;          // captions bf16
constexpr size_t GBOFF = BBOFF + (size_t)Nn * Dn / 2;  // Gb bf16 [In][48][64]
constexpr size_t CNOFF = GBOFF + (size_t)In * 48 * 64 / 2;
constexpr size_t WSFLOATS = CNOFF + (size_t)Cn * Ln;   // ~7.6 MB
constexpr float EPSf = 1e-8f, LLSE = 6.0f, LSM = 9.0f, SLOPE = 0.1f;

using short8 = __attribute__((ext_vector_type(8))) short;
using f32x4  = __attribute__((ext_vector_type(4))) float;

__device__ __forceinline__ float dot4(float4 a, float4 b) {
  return a.x * b.x + a.y * b.y + a.z * b.z + a.w * b.w;
}

__device__ __forceinline__ unsigned short f2bf(float x) {   // RNE
  union { float f; unsigned u; } v; v.f = x;
  unsigned r = v.u + 0x7fffu + ((v.u >> 16) & 1u);
  return (unsigned short)(r >> 16);
}

__device__ __forceinline__ short8 pack8(float4 u, float4 v) {
  short8 s;
  s[0] = (short)f2bf(u.x); s[1] = (short)f2bf(u.y); s[2] = (short)f2bf(u.z); s[3] = (short)f2bf(u.w);
  s[4] = (short)f2bf(v.x); s[5] = (short)f2bf(v.y); s[6] = (short)f2bf(v.z); s[7] = (short)f2bf(v.w);
  return s;
}

// ---------------------------------------------------------------------------
// Prepass, grid 704:
//  blocks 0..127   : per-image fp32->bf16 cvt (to ws) + G = img.img^T via MFMA
//  blocks 128..639 : caption fp32->bf16 cvt
//  blocks 640..703 : caption sq-norms (fp32)
// ---------------------------------------------------------------------------
extern "C" __global__ __launch_bounds__(256, 2)
void scan_pre(const float* __restrict__ images, const float* __restrict__ captions,
              float* __restrict__ ws)
{
  __shared__ unsigned short sI[48 * 520];   // 49,920 B (rows 36..47 zero)
  const int tid = threadIdx.x;
  const int bx = blockIdx.x;
  const short8 z8 = {0, 0, 0, 0, 0, 0, 0, 0};

  if (bx < 128) {
    const int i = bx;
    const float* gi = images + (size_t)i * Rn * Dn;
    unsigned short* Ab = (unsigned short*)(ws + ABOFF) + (size_t)i * Rn * Dn;
    // cvt + stage (36*512/8 = 2304 chunks, 9/thread)
    for (int q = 0; q < 9; ++q) {
      int ch = tid + q * 256;
      int r = ch >> 6, c8 = (ch & 63) * 8;
      float4 u = *reinterpret_cast<const float4*>(gi + r * Dn + c8);
      float4 v = *reinterpret_cast<const float4*>(gi + r * Dn + c8 + 4);
      short8 p = pack8(u, v);
      *reinterpret_cast<short8*>(Ab + r * Dn + c8) = p;
      *reinterpret_cast<short8*>(&sI[r * 520 + c8]) = p;
    }
    // zero pad rows 36..47 (768 chunks, 3/thread)
    for (int q = 0; q < 3; ++q) {
      int ch = tid + q * 256;
      int r = 36 + (ch >> 6), c8 = (ch & 63) * 8;
      *reinterpret_cast<short8*>(&sI[r * 520 + c8]) = z8;
    }
    __syncthreads();
    // G via MFMA: 9 tiles (mt,nt), wave wv handles tiles wv, wv+4, wv+8
    const int lane = tid & 63, wv = tid >> 6;
    const int lr = lane & 15, lk = lane >> 4;
    unsigned short* gb = (unsigned short*)(ws + GBOFF) + (size_t)i * 48 * 64;
    for (int t = wv; t < 9; t += 4) {
      const int mt = t / 3, nt = t - mt * 3;
      f32x4 acc = {0.f, 0.f, 0.f, 0.f};
      for (int k = 0; k < 16; ++k) {
        short8 af = *reinterpret_cast<const short8*>(&sI[(mt * 16 + lr) * 520 + k * 32 + lk * 8]);
        short8 bf = *reinterpret_cast<const short8*>(&sI[(nt * 16 + lr) * 520 + k * 32 + lk * 8]);
        acc = __builtin_amdgcn_mfma_f32_16x16x32_bf16(af, bf, acc, 0, 0, 0);
      }
      // G symmetric -> layout transpose-safe; pad rows/cols come out as 0
      #pragma unroll
      for (int j = 0; j < 4; ++j)
        gb[(mt * 16 + lk * 4 + j) * 64 + nt * 16 + lr] = f2bf(acc[j]);
    }
    // zero cols 48..63 of all 48 rows (96 short8)
    if (tid < 96) {
      int r = tid >> 1, h = tid & 1;
      *reinterpret_cast<short8*>(gb + r * 64 + 48 + h * 8) = z8;
    }
    return;
  }
  if (bx < 640) {                                  // caption cvt
    const int chunk = (bx - 128) * 256 + tid;      // 0..131071
    unsigned short* Bbd = (unsigned short*)(ws + BBOFF);
    size_t off = (size_t)chunk * 8;
    float4 u = *reinterpret_cast<const float4*>(captions + off);
    float4 v = *reinterpret_cast<const float4*>(captions + off + 4);
    *reinterpret_cast<short8*>(Bbd + off) = pack8(u, v);
    return;
  }
  {                                                // caption sq-norms
    const int c = bx - 640;
    const float* gc = captions + (size_t)c * Ln * Dn;
    const int l = tid >> 3, p = tid & 7;
    float s = 0.f;
    #pragma unroll
    for (int t = 0; t < 16; ++t) {
      float4 v = *reinterpret_cast<const float4*>(gc + l * Dn + p * 64 + t * 4);
      s += dot4(v, v);
    }
    s += __shfl_xor(s, 1, 64); s += __shfl_xor(s, 2, 64); s += __shfl_xor(s, 4, 64);
    if (p == 0) ws[CNOFF + c * Ln + l] = s;
  }
}

// ---------------------------------------------------------------------------
// Fused (round-7 structure, proven 42 us): block = 1 image x 4 captions
// (wave = caption). A+B staged in LDS, 2 barriers/K-step; ET overlaid on Bl.
// Only change vs r7: __expf / __logf.
// ---------------------------------------------------------------------------
extern "C" __global__ __launch_bounds__(256, 2)
void scan_fused(const float* __restrict__ ws, const int* __restrict__ cap_lens,
                float* __restrict__ out)
{
  __shared__ unsigned short Al[48 * 72];    //  6.9 KB
  __shared__ unsigned short Bl[128 * 72];   // 18.4 KB (reused for E^T per wave)
  const unsigned short* Ab = (const unsigned short*)(ws + ABOFF);
  const unsigned short* Bb = (const unsigned short*)(ws + BBOFF);
  const unsigned short* GbAll = (const unsigned short*)(ws + GBOFF);
  const float* cnArr = ws + CNOFF;

  const int tid = threadIdx.x;
  int bid = blockIdx.x;                      // 2048 blocks; 8 XCD chunks of 256
  bid = (bid & 7) * 256 + (bid >> 3);
  const int ig = bid >> 4;
  const int cg = bid & 15;
  const int lane = tid & 63, wv = tid >> 6;
  const int lr = lane & 15, lk = lane >> 4;
  const int cap = cg * 4 + wv;
  const int len = cap_lens[cap];

  const int ar = tid >> 2, aq = tid & 3;
  const int br = tid >> 1, bh = tid & 1;

  const unsigned short* gA = Ab + ((size_t)ig * 36 + (ar < 36 ? ar : 0)) * Dn + aq * 16;
  const unsigned short* gB = Bb + ((size_t)(cg * 128) + br) * Dn + bh * 32;
  const bool aValid = (tid < 192) && (ar < 36);
  const bool aPad   = (tid < 192) && (ar >= 36);

  f32x4 acc[3][2];
  #pragma unroll
  for (int x = 0; x < 3; ++x)
    #pragma unroll
    for (int y = 0; y < 2; ++y) acc[x][y] = {0.f, 0.f, 0.f, 0.f};

  for (int k0 = 0; k0 < Dn; k0 += 64) {
    short8 a0 = {0,0,0,0,0,0,0,0}, a1 = {0,0,0,0,0,0,0,0};
    if (aValid) {
      a0 = *reinterpret_cast<const short8*>(gA + k0);
      a1 = *reinterpret_cast<const short8*>(gA + k0 + 8);
    }
    short8 b0 = *reinterpret_cast<const short8*>(gB + k0);
    short8 b1 = *reinterpret_cast<const short8*>(gB + k0 + 8);
    short8 b2 = *reinterpret_cast<const short8*>(gB + k0 + 16);
    short8 b3 = *reinterpret_cast<const short8*>(gB + k0 + 24);
    __syncthreads();                          // prior K-step's ds_reads done
    if (aValid || aPad) {
      *reinterpret_cast<short8*>(&Al[ar * 72 + aq * 16])     = a0;
      *reinterpret_cast<short8*>(&Al[ar * 72 + aq * 16 + 8]) = a1;
    }
    {
      unsigned short* w = &Bl[br * 72 + bh * 32];
      *reinterpret_cast<short8*>(w)      = b0;
      *reinterpret_cast<short8*>(w + 8)  = b1;
      *reinterpret_cast<short8*>(w + 16) = b2;
      *reinterpret_cast<short8*>(w + 24) = b3;
    }
    __syncthreads();
    #pragma unroll
    for (int ks = 0; ks < 2; ++ks) {
      short8 af[3], bf[2];
      #pragma unroll
      for (int x = 0; x < 3; ++x)
        af[x] = *reinterpret_cast<const short8*>(&Al[(x * 16 + lr) * 72 + ks * 32 + lk * 8]);
      #pragma unroll
      for (int y = 0; y < 2; ++y)
        bf[y] = *reinterpret_cast<const short8*>(&Bl[(wv * 32 + y * 16 + lr) * 72 + ks * 32 + lk * 8]);
      #pragma unroll
      for (int x = 0; x < 3; ++x)
        #pragma unroll
        for (int y = 0; y < 2; ++y)
          acc[x][y] = __builtin_amdgcn_mfma_f32_16x16x32_bf16(af[x], bf[y], acc[x][y], 0, 0, 0);
    }
  }

  const unsigned short* Gb = GbAll + (size_t)ig * 48 * 64;
  short8 gfr[3][2];
  #pragma unroll
  for (int x = 0; x < 3; ++x)
    #pragma unroll
    for (int ks = 0; ks < 2; ++ks)
      gfr[x][ks] = *reinterpret_cast<const short8*>(Gb + (x * 16 + lr) * 64 + ks * 32 + lk * 8);
  const float cn0 = cnArr[cap * 32 + lr];
  const float cn1 = cnArr[cap * 32 + 16 + lr];

  float s[3][2][4];
  #pragma unroll
  for (int x = 0; x < 3; ++x)
    #pragma unroll
    for (int y = 0; y < 2; ++y) {
      const int l = y * 16 + lr;
      #pragma unroll
      for (int j = 0; j < 4; ++j) {
        float v = acc[x][y][j];
        v = v > 0.f ? v : SLOPE * v;
        if (l >= len) v = 0.f;
        s[x][y][j] = v;
      }
    }

  float zinv[3][4];
  #pragma unroll
  for (int x = 0; x < 3; ++x)
    #pragma unroll
    for (int j = 0; j < 4; ++j) {
      float t = s[x][0][j] * s[x][0][j] + s[x][1][j] * s[x][1][j];
      t += __shfl_xor(t, 1, 64); t += __shfl_xor(t, 2, 64);
      t += __shfl_xor(t, 4, 64); t += __shfl_xor(t, 8, 64);
      zinv[x][j] = LSM / (sqrtf(t) + EPSf);
    }

  const bool x2ok = (lk == 0);
  float mcol[2] = {-1e30f, -1e30f};
  #pragma unroll
  for (int x = 0; x < 3; ++x)
    #pragma unroll
    for (int y = 0; y < 2; ++y)
      #pragma unroll
      for (int j = 0; j < 4; ++j) {
        float zz = s[x][y][j] * zinv[x][j];
        s[x][y][j] = zz;
        if (x < 2 || x2ok) mcol[y] = fmaxf(mcol[y], zz);
      }
  #pragma unroll
  for (int y = 0; y < 2; ++y) {
    mcol[y] = fmaxf(mcol[y], __shfl_xor(mcol[y], 16, 64));
    mcol[y] = fmaxf(mcol[y], __shfl_xor(mcol[y], 32, 64));
  }

  float e[3][2][4];
  float esum[2] = {0.f, 0.f}, num[2] = {0.f, 0.f};
  #pragma unroll
  for (int x = 0; x < 3; ++x)
    #pragma unroll
    for (int y = 0; y < 2; ++y)
      #pragma unroll
      for (int j = 0; j < 4; ++j) {
        float ev = (x < 2 || x2ok) ? __expf(s[x][y][j] - mcol[y]) : 0.f;
        e[x][y][j] = ev;
        esum[y] += ev;
        num[y] = fmaf(ev, acc[x][y][j], num[y]);
      }
  #pragma unroll
  for (int y = 0; y < 2; ++y) {
    esum[y] += __shfl_xor(esum[y], 16, 64); esum[y] += __shfl_xor(esum[y], 32, 64);
    num[y]  += __shfl_xor(num[y], 16, 64);  num[y]  += __shfl_xor(num[y], 32, 64);
  }

  unsigned short* ET = &Bl[(wv * 32) * 72];
  {
    const int zl = lane >> 1, zs = lane & 1;
    short8 zero = {0,0,0,0,0,0,0,0};
    *reinterpret_cast<short8*>(&ET[zl * 72 + 48 + zs * 8]) = zero;
  }
  #pragma unroll
  for (int x = 0; x < 3; ++x)
    #pragma unroll
    for (int y = 0; y < 2; ++y)
      #pragma unroll
      for (int j = 0; j < 4; ++j)
        ET[(y * 16 + lr) * 72 + (x * 16 + lk * 4 + j)] = f2bf(e[x][y][j]);
  __syncthreads();

  f32x4 vac[3][2];
  #pragma unroll
  for (int x = 0; x < 3; ++x)
    #pragma unroll
    for (int y = 0; y < 2; ++y) vac[x][y] = {0.f, 0.f, 0.f, 0.f};
  #pragma unroll
  for (int ks = 0; ks < 2; ++ks) {
    short8 efr[2];
    #pragma unroll
    for (int y = 0; y < 2; ++y)
      efr[y] = *reinterpret_cast<const short8*>(&ET[(y * 16 + lr) * 72 + ks * 32 + lk * 8]);
    #pragma unroll
    for (int x = 0; x < 3; ++x)
      #pragma unroll
      for (int y = 0; y < 2; ++y)
        vac[x][y] = __builtin_amdgcn_mfma_f32_16x16x32_bf16(gfr[x][ks], efr[y], vac[x][y], 0, 0, 0);
  }
  float wn[2] = {0.f, 0.f};
  #pragma unroll
  for (int x = 0; x < 3; ++x)
    #pragma unroll
    for (int y = 0; y < 2; ++y)
      #pragma unroll
      for (int j = 0; j < 4; ++j)
        wn[y] = fmaf(e[x][y][j], vac[x][y][j], wn[y]);
  #pragma unroll
  for (int y = 0; y < 2; ++y) {
    wn[y] += __shfl_xor(wn[y], 16, 64); wn[y] += __shfl_xor(wn[y], 32, 64);
  }

  float sc[2];
  #pragma unroll
  for (int y = 0; y < 2; ++y) {
    const int l = y * 16 + lr;
    const float cn = y ? cn1 : cn0;
    float inv = 1.f / esum[y];
    float nm = num[y] * inv;
    float w = fmaxf(wn[y], 0.f) * inv * inv;
    float den = fmaxf(sqrtf(cn), EPSf) * fmaxf(sqrtf(w), EPSf);
    sc[y] = (l < len) ? (nm / den) * LLSE : -INFINITY;
  }
  float mx = fmaxf(sc[0], sc[1]);
  mx = fmaxf(mx, __shfl_xor(mx, 1, 64)); mx = fmaxf(mx, __shfl_xor(mx, 2, 64));
  mx = fmaxf(mx, __shfl_xor(mx, 4, 64)); mx = fmaxf(mx, __shfl_xor(mx, 8, 64));
  float ex = __expf(sc[0] - mx) + __expf(sc[1] - mx);
  ex += __shfl_xor(ex, 1, 64); ex += __shfl_xor(ex, 2, 64);
  ex += __shfl_xor(ex, 4, 64); ex += __shfl_xor(ex, 8, 64);
  if (lane == 0) out[ig * Cn + cap] = (mx + __logf(ex)) / LLSE;
}

extern "C" void kernel_launch(void* const* d_in, const int* in_sizes, int n_in,
                              void* d_out, int out_size, void* d_ws, size_t ws_size,
                              hipStream_t stream) {
  const float* images   = (const float*)d_in[0];
  const float* captions = (const float*)d_in[1];
  const int*   cap_lens = (const int*)d_in[2];
  float* out = (float*)d_out;
  float* ws  = (float*)d_ws;
  if (ws_size < WSFLOATS * sizeof(float)) return;

  hipLaunchKernelGGL(scan_pre, dim3(704), dim3(256), 0, stream,
                     images, captions, ws);
  hipLaunchKernelGGL(scan_fused, dim3(In * 16), dim3(256), 0, stream,
                     ws, cap_lens, out);
}